// Round 10
// baseline (203.495 us; speedup 1.0000x reference)
//
#include <hip/hip_runtime.h>

#define NVOX 200000
#define KOFF 9
#define NSHARD 32
#define BN_EPS 1e-5f

typedef unsigned short u16;
typedef __bf16 bf16x8 __attribute__((ext_vector_type(8)));
typedef float f32x4 __attribute__((ext_vector_type(4)));
typedef unsigned int u32x4v __attribute__((ext_vector_type(4)));
typedef u16 u16x8 __attribute__((ext_vector_type(8)));

__device__ __forceinline__ float lrelu(float x) { return x > 0.0f ? x : 0.01f * x; }
__device__ __forceinline__ float bf2f(u16 h) { return __uint_as_float(((unsigned)h) << 16); }
__device__ __forceinline__ u16 f2bf(float x) {   // round-nearest-even
    unsigned u = __float_as_uint(x);
    u += 0x7fffu + ((u >> 16) & 1u);
    return (u16)(u >> 16);
}
__device__ __forceinline__ unsigned pkbf(float a, float b) {
    return (unsigned)f2bf(a) | ((unsigned)f2bf(b) << 16);
}

// Row-partitioned, barrier-free MFMA sparse-conv:
//  - wave w owns rows 16w..16w+15 of the 64-voxel tile (ALL 64 cout cols)
//  - gather: wave-cooperative global->REGISTER ring (3 slots, distance-3
//    prefetch); 4 lanes x 16B per row; no LDS staging, NO barriers in K-loop
//  - A-fragments built by in-wave __shfl (bpermute): lane(rl,q) takes the
//    16B chunk of row rl at k-offset q*8 from lane rl*4+q
//  - B-fragments: pre-fragmented weight tables (lane-order) -> coalesced
//    16B/lane L2-hot loads; folded-BN bias via register mask MFMA
//  - epilogue: acc -> LDS tile -> full-line NT stores; shfl-reduced BN stats
//    -> 32-way sharded atomics (single barrier in whole kernel)
template<int CIN, bool BIAS, int MINB>
__global__ __launch_bounds__(256, MINB) void conv_mfma(
    const u16* __restrict__ X0, const u16* __restrict__ X1,
    const int* __restrict__ nbr0, const int* __restrict__ nbr1,
    const int* __restrict__ msk0, const int* __restrict__ msk1,
    const u16* __restrict__ Wfrag,   // [2][KOFF][4cc][NCH][64][8] bf16 (lane-order)
    const u16* __restrict__ BWfrag,  // [2][4cc][64][8] bf16 (BIAS only)
    u16* __restrict__ outH0, u16* __restrict__ outH1,
    float* __restrict__ outF0, float* __restrict__ outF1,
    float* __restrict__ st0, float* __restrict__ st1)
{
    constexpr int NCH = CIN / 32;
    const int br = blockIdx.y;
    const u16* X = br ? X1 : X0;
    const int* nbr = br ? nbr1 : nbr0;
    const int* msk = br ? msk1 : msk0;
    const u16* Wf = Wfrag + (size_t)br * KOFF * 4 * NCH * 64 * 8;
    u16* outH = br ? outH1 : outH0;
    float* outF = br ? outF1 : outF0;
    float* st = br ? st1 : st0;

    __shared__ __align__(16) unsigned char sraw[17408];  // out tile (f32 64x68 max)
    __shared__ float red[512];                           // [4w][{ps,pss}][64]

    const int tid = threadIdx.x;
    const int w  = tid >> 6;
    const int l  = tid & 63;
    const int rl = l & 15;
    const int q  = l >> 4;
    const int n0 = blockIdx.x * 64;
    const int rbase = n0 + w * 16;
    const int grow = l >> 2;        // lane's gather row (0..15 within wave)
    const int gch  = l & 3;         // lane's 16B chunk within the row

    // ---- neighbor indices for this wave's 16 rows (mask folded to -1)
    int srcs[KOFF];
    #pragma unroll
    for (int k = 0; k < KOFF; ++k) {
        const int m  = msk[k * NVOX + rbase + grow];
        const int nb = nbr[k * NVOX + rbase + grow];
        srcs[k] = m ? nb : -1;
    }
    int bits = 0;
    if constexpr (BIAS) {
        #pragma unroll
        for (int k = 0; k < KOFF; ++k) bits |= (srcs[k] >= 0) ? (1 << k) : 0;
    }

    // ---- register gather ring (3 slots, NCH uint4 each)
    uint4 g[3][NCH];
    auto issue = [&](int k, int s) {
        const int src = srcs[k];
        #pragma unroll
        for (int p = 0; p < NCH; ++p) g[s][p] = make_uint4(0u, 0u, 0u, 0u);
        if (src >= 0) {
            const u16* ptr = X + (size_t)src * CIN + gch * 8;
            #pragma unroll
            for (int p = 0; p < NCH; ++p)
                g[s][p] = *(const uint4*)(ptr + p * 32);
        }
    };

    f32x4 acc[4] = {};
    issue(0, 0); issue(1, 1); issue(2, 2);
    const int asrc = rl * 4 + q;     // source lane for A-fragment shuffle
    #pragma unroll
    for (int k = 0; k < KOFF; ++k) {
        bf16x8 afr[NCH];
        #pragma unroll
        for (int ch = 0; ch < NCH; ++ch) {
            uint4 v = g[k % 3][ch];
            uint4 s;
            s.x = (unsigned)__shfl((int)v.x, asrc);
            s.y = (unsigned)__shfl((int)v.y, asrc);
            s.z = (unsigned)__shfl((int)v.z, asrc);
            s.w = (unsigned)__shfl((int)v.w, asrc);
            afr[ch] = __builtin_bit_cast(bf16x8, s);
        }
        if (k + 3 < KOFF) issue(k + 3, k % 3);   // slot just consumed
        #pragma unroll
        for (int cc = 0; cc < 4; ++cc)
            #pragma unroll
            for (int ch = 0; ch < NCH; ++ch) {
                bf16x8 bfr = *(const bf16x8*)(Wf +
                    ((((size_t)k * 4 + cc) * NCH + ch) * 64 + l) * 8);
                acc[cc] = __builtin_amdgcn_mfma_f32_16x16x32_bf16(afr[ch], bfr, acc[cc], 0, 0, 0);
            }
    }

    // ---- folded-BN bias: acc += M(mask 0/1) x BW (register-built A-fragment)
    if constexpr (BIAS) {
        const int mb = __shfl(bits, rl * 4);     // row rl's mask bits
        u16x8 mu;
        #pragma unroll
        for (int j = 0; j < 8; ++j)
            mu[j] = (((unsigned)mb >> (q * 8 + j)) & 1u) ? (u16)0x3F80 : (u16)0;
        bf16x8 mf = __builtin_bit_cast(bf16x8, mu);
        #pragma unroll
        for (int cc = 0; cc < 4; ++cc) {
            bf16x8 bw = *(const bf16x8*)(BWfrag + (((size_t)br * 4 + cc) * 64 + l) * 8);
            acc[cc] = __builtin_amdgcn_mfma_f32_16x16x32_bf16(mf, bw, acc[cc], 0, 0, 0);
        }
    }

    // ---- epilogue: LeakyReLU -> LDS tile + per-column BN partials
    u16*   sO16 = (u16*)sraw;        // [64][72] bf16 tile
    float* sO32 = (float*)sraw;      // [64][68] f32 tile
    #pragma unroll
    for (int cc = 0; cc < 4; ++cc) {
        float s = 0.f, s2 = 0.f;
        #pragma unroll
        for (int i = 0; i < 4; ++i) {
            float v = lrelu(acc[cc][i]);
            s += v; s2 += v * v;
            const int row = w * 16 + q * 4 + i;
            const int col = cc * 16 + rl;
            if (outH) sO16[row * 72 + col] = f2bf(v);
            else      sO32[row * 68 + col] = v;
        }
        s  += __shfl_xor(s, 16);  s  += __shfl_xor(s, 32);
        s2 += __shfl_xor(s2, 16); s2 += __shfl_xor(s2, 32);
        if (q == 0) {
            red[(w * 2) * 64 + cc * 16 + rl]     = s;
            red[(w * 2 + 1) * 64 + cc * 16 + rl] = s2;
        }
    }
    __syncthreads();

    // ---- coalesced full-line NT stores + cross-wave stat reduce + shard atomics
    if (outH) {
        #pragma unroll
        for (int p = 0; p < 2; ++p) {
            const int row = (tid >> 3) + p * 32, seg = tid & 7;
            uint4 v = *(const uint4*)(sO16 + row * 72 + seg * 8);
            __builtin_nontemporal_store(__builtin_bit_cast(u32x4v, v),
                (u32x4v*)(outH + (size_t)(n0 + row) * 64 + seg * 8));
        }
    } else {
        #pragma unroll
        for (int p = 0; p < 4; ++p) {
            const int row = (tid >> 4) + p * 16, seg = tid & 15;
            float4 v = *(const float4*)(sO32 + row * 68 + seg * 4);
            __builtin_nontemporal_store(__builtin_bit_cast(f32x4, v),
                (f32x4*)(outF + (size_t)(n0 + row) * 64 + seg * 4));
        }
    }
    if (tid < 128) {
        const int arr = tid >> 6, d = tid & 63;
        float s = 0.f;
        #pragma unroll
        for (int ww = 0; ww < 4; ++ww) s += red[(ww * 2 + arr) * 64 + d];
        const int shard = blockIdx.x & (NSHARD - 1);
        atomicAdd(st + shard * 512 + arr * 64 + d, s);
    }
}

// b<144: stage-A weight fragments WtAfrag[br][k][cc][l][j] = bf16(W[k][cin][cout]),
//        cin=(l>>4)*8+j, cout=cc*16+(l&15);
// b in [144,208): zero sharded stats;  b>=208: feats f32 -> bf16, grid-stride.
__global__ void prep0(const float* __restrict__ W1, const float* __restrict__ W2,
                      const float* __restrict__ feats,
                      u16* __restrict__ WtAfrag, float* __restrict__ stats,
                      u16* __restrict__ feats16)
{
    const int b = blockIdx.x;
    const int t = threadIdx.x;
    if (b < 144) {
        const int i = b * 256 + t;                 // 2*9*4*64*8 = 36864 exactly
        const int br = i / 18432;
        int r = i % 18432;
        const int k = r / 2048; r %= 2048;
        const int cc = r / 512; r %= 512;
        const int l = r / 8;
        const int j = r % 8;
        const int rl = l & 15, q = l >> 4;
        const int cin = q * 8 + j;
        const int cout = cc * 16 + rl;
        const float* W = br ? W2 : W1;
        WtAfrag[i] = f2bf(W[((size_t)k * 32 + cin) * 64 + cout]);
        return;
    }
    if (b < 208) {                                 // 64*256 = 16384 = NSHARD*512
        stats[(b - 144) * 256 + t] = 0.f;
        return;
    }
    const int stride = (gridDim.x - 208) * 256;
    for (int i = (b - 208) * 256 + t; i < NVOX * 32 / 8; i += stride) {
        const float4 f0 = ((const float4*)feats)[i * 2];
        const float4 f1 = ((const float4*)feats)[i * 2 + 1];
        ((uint4*)feats16)[i] = make_uint4(pkbf(f0.x, f0.y), pkbf(f0.z, f0.w),
                                          pkbf(f1.x, f1.y), pkbf(f1.z, f1.w));
    }
}

// finalize stage-A BN (sum shards, in LDS) + emit stage-B fragment tables:
//  WtBfrag[br][k][cc][ch][l][j] = bf16(W[k][cin][cout]*a[cin]), cin=ch*32+(l>>4)*8+j
//  BWfrag[br][cc][l][j] = bf16(sum_c b'[c]*W[kk][c][cout]), kk=(l>>4)*8+j (<KOFF else 0)
__global__ void wprepB(const float* __restrict__ W12, const float* __restrict__ W3,
                       const float* __restrict__ stats,
                       const float* __restrict__ g0, const float* __restrict__ b0,
                       const float* __restrict__ g1, const float* __restrict__ b1,
                       u16* __restrict__ WtBfrag, u16* __restrict__ BWfrag)
{
    __shared__ float sa[256];                 // [br][{a[64], b'[64]}]
    const int t = threadIdx.x;
    if (t < 128) {
        const int brw = t >> 6, d = t & 63;
        float s = 0.f, ss = 0.f;
        for (int sh = 0; sh < NSHARD; ++sh) {
            s  += stats[sh * 512 + brw * 128 + d];
            ss += stats[sh * 512 + brw * 128 + 64 + d];
        }
        const float* g = brw ? g1 : g0;
        const float* bb = brw ? b1 : b0;
        const float inv_n = 1.0f / (float)NVOX;
        float mu  = s * inv_n;
        float var = ss * inv_n - mu * mu;
        float a = g[d] * rsqrtf(var + BN_EPS);
        sa[brw * 128 + d] = a;
        sa[brw * 128 + 64 + d] = bb[d] - mu * a;
    }
    __syncthreads();
    const int i = blockIdx.x * 256 + t;
    if (i < 9216) {                            // 2*9*4*2*64 fragment rows
        const int br = i / 4608;
        int r = i % 4608;
        const int k = r / 512; r %= 512;
        const int cc = r / 128; r %= 128;
        const int ch = r / 64;
        const int l = r % 64;
        const int rl = l & 15, q = l >> 4;
        const int cout = cc * 16 + rl;
        const float* W = br ? W3 : W12;
        const float* a = sa + br * 128;
        u16 o[8];
        #pragma unroll
        for (int j = 0; j < 8; ++j) {
            const int cin = ch * 32 + q * 8 + j;
            o[j] = f2bf(W[((size_t)k * 64 + cin) * 64 + cout] * a[cin]);
        }
        *(uint4*)(WtBfrag + (size_t)i * 8) = make_uint4(
            (unsigned)o[0] | ((unsigned)o[1] << 16), (unsigned)o[2] | ((unsigned)o[3] << 16),
            (unsigned)o[4] | ((unsigned)o[5] << 16), (unsigned)o[6] | ((unsigned)o[7] << 16));
    } else if (i < 9216 + 512) {               // 2*4*64 BW fragment rows
        const int i2 = i - 9216;
        const int br = i2 / 256;
        int r = i2 % 256;
        const int cc = r / 64;
        const int l = r % 64;
        const int rl = l & 15, q = l >> 4;
        const int cout = cc * 16 + rl;
        const float* W = br ? W3 : W12;
        const float* bb = sa + br * 128 + 64;
        u16 o[8];
        #pragma unroll
        for (int j = 0; j < 8; ++j) {
            const int kk = q * 8 + j;
            float bw = 0.f;
            if (kk < KOFF)
                for (int c = 0; c < 64; ++c)
                    bw += bb[c] * W[((size_t)kk * 64 + c) * 64 + cout];
            o[j] = f2bf(bw);
        }
        *(uint4*)(BWfrag + (size_t)i2 * 8) = make_uint4(
            (unsigned)o[0] | ((unsigned)o[1] << 16), (unsigned)o[2] | ((unsigned)o[3] << 16),
            (unsigned)o[4] | ((unsigned)o[5] << 16), (unsigned)o[6] | ((unsigned)o[7] << 16));
    }
}

// finalize stage-B BN (sum shards) + out = aff2(ys) + aff3(yr), in place over yr (= d_out)
__global__ void combine_kernel(const u16* __restrict__ ys, float* __restrict__ yr,
                               const float* __restrict__ stats,
                               const float* __restrict__ g02, const float* __restrict__ b02,
                               const float* __restrict__ g2, const float* __restrict__ b2)
{
    __shared__ float sc[256];                 // [br][{a[64], b'[64]}]; br0=ys, br1=yr
    const int t = threadIdx.x;
    if (t < 128) {
        const int brw = t >> 6, d = t & 63;
        float s = 0.f, ss = 0.f;
        for (int sh = 0; sh < NSHARD; ++sh) {
            s  += stats[sh * 512 + 256 + brw * 128 + d];
            ss += stats[sh * 512 + 256 + brw * 128 + 64 + d];
        }
        const float* g = brw ? g2 : g02;
        const float* b = brw ? b2 : b02;
        const float inv_n = 1.0f / (float)NVOX;
        float mu  = s * inv_n;
        float var = ss * inv_n - mu * mu;
        float a = g[d] * rsqrtf(var + BN_EPS);
        sc[brw * 128 + d] = a;
        sc[brw * 128 + 64 + d] = b[d] - mu * a;
    }
    __syncthreads();
    const int total = NVOX * 64 / 4;
    for (int i = blockIdx.x * blockDim.x + t; i < total; i += gridDim.x * blockDim.x) {
        const int dq = (i & 15) * 4;
        ushort4 sh = reinterpret_cast<const ushort4*>(ys)[i];
        float4 r = reinterpret_cast<const float4*>(yr)[i];
        float4 a2 = *(const float4*)(sc + dq);
        float4 b2v = *(const float4*)(sc + 64 + dq);
        float4 a3 = *(const float4*)(sc + 128 + dq);
        float4 b3v = *(const float4*)(sc + 128 + 64 + dq);
        f32x4 o;
        o.x = fmaf(a2.x, bf2f(sh.x), b2v.x) + fmaf(a3.x, r.x, b3v.x);
        o.y = fmaf(a2.y, bf2f(sh.y), b2v.y) + fmaf(a3.y, r.y, b3v.y);
        o.z = fmaf(a2.z, bf2f(sh.z), b2v.z) + fmaf(a3.z, r.z, b3v.z);
        o.w = fmaf(a2.w, bf2f(sh.w), b2v.w) + fmaf(a3.w, r.w, b3v.w);
        __builtin_nontemporal_store(o, (f32x4*)(yr + (size_t)i * 4));
    }
}

extern "C" void kernel_launch(void* const* d_in, const int* in_sizes, int n_in,
                              void* d_out, int out_size, void* d_ws, size_t ws_size,
                              hipStream_t stream) {
    const float* feats = (const float*)d_in[0];
    const float* W1    = (const float*)d_in[1];
    const float* W12   = (const float*)d_in[2];
    const float* W2    = (const float*)d_in[3];
    const float* W3    = (const float*)d_in[4];
    const float* g0  = (const float*)d_in[5];
    const float* b0  = (const float*)d_in[6];
    const float* g02 = (const float*)d_in[7];
    const float* b02 = (const float*)d_in[8];
    const float* g1  = (const float*)d_in[9];
    const float* b1  = (const float*)d_in[10];
    const float* g2  = (const float*)d_in[11];
    const float* b2  = (const float*)d_in[12];
    const int* nbrA  = (const int*)d_in[13];
    const int* maskA = (const int*)d_in[14];   // bool delivered as int32
    const int* nbrB  = (const int*)d_in[15];
    const int* maskB = (const int*)d_in[16];

    // ws layout: bf16 activations + fragmented bf16 weights + sharded stats (~77 MB).
    // feats16 aliases ys: feats16 read only in stage A, ys written only in stage B.
    const size_t buf = (size_t)NVOX * 64;
    u16* y1  = (u16*)d_ws;
    u16* y2  = y1 + buf;
    u16* ys  = y2 + buf;
    u16* feats16 = ys;                   // alias (NVOX*32 u16)
    u16* WtA = ys + buf;                 // 2*9*4*64*8   = 36864
    u16* WtB = WtA + 2 * KOFF * 4 * 64 * 8;      // 2*9*4*2*64*8 = 73728
    u16* BWf = WtB + 2 * KOFF * 4 * 2 * 64 * 8;  // 2*4*64*8     = 4096
    float* stats = (float*)(BWf + 2 * 4 * 64 * 8); // NSHARD x [4 x {sum,sumsq}[64]]
    float* outf  = (float*)d_out;        // stage-B resA output lives in d_out

    dim3 gA(NVOX / 64, 2);

    prep0<<<2000, 256, 0, stream>>>(W1, W2, feats, WtA, stats, feats16);

    // stage A: y1 = lrelu(conv(feats,nbrA,W1)); y2 = lrelu(conv(feats,nbrB,W2))
    conv_mfma<32, false, 6><<<gA, 256, 0, stream>>>(
        feats16, feats16, nbrA, nbrB, maskA, maskB, WtA, nullptr,
        y1, y2, nullptr, nullptr, stats, stats + 128);

    wprepB<<<38, 256, 0, stream>>>(W12, W3, stats, g0, b0, g1, b1, WtB, BWf);

    // stage B: ys = lrelu(conv(bn(y1),nbrB,W12)); outf = lrelu(conv(bn(y2),nbrA,W3))
    conv_mfma<64, true, 5><<<gA, 256, 0, stream>>>(
        y1, y2, nbrB, nbrA, maskB, maskA, WtB, BWf,
        ys, nullptr, nullptr, outf, stats + 256, stats + 384);

    combine_kernel<<<1024, 256, 0, stream>>>(ys, outf, stats, g02, b02, g2, b2);
}

// Round 11
// 191.202 us; speedup vs baseline: 1.0643x; 1.0643x over previous
//
#include <hip/hip_runtime.h>

#define NVOX 200000
#define KOFF 9
#define NSHARD 32
#define BN_EPS 1e-5f

typedef unsigned short u16;
typedef __bf16 bf16x8 __attribute__((ext_vector_type(8)));
typedef float f32x4 __attribute__((ext_vector_type(4)));
typedef unsigned int u32x4v __attribute__((ext_vector_type(4)));

__device__ __forceinline__ float lrelu(float x) { return x > 0.0f ? x : 0.01f * x; }
__device__ __forceinline__ float bf2f(u16 h) { return __uint_as_float(((unsigned)h) << 16); }
__device__ __forceinline__ u16 f2bf(float x) {   // round-nearest-even
    unsigned u = __float_as_uint(x);
    u += 0x7fffu + ((u >> 16) & 1u);
    return (u16)(u >> 16);
}
__device__ __forceinline__ unsigned pkbf(float a, float b) {
    return (unsigned)f2bf(a) | ((unsigned)f2bf(b) << 16);
}

// MFMA sparse-conv (r7 ring pipeline + LDS-tile store epilogue; best structure):
//  - all 9 mask/nbr indices preloaded (independent loads)
//  - gather ring: 3 LDS slots, loads for offset k issued at iteration k-2,
//    ONE barrier per iteration
//  - BN stats: 32-way sharded atomics
//  - epilogue: acc -> LDS tile -> full-128B-line NT stores
// 64 voxels x 64 cout per block, 4 waves; wave w owns cols 16w..16w+15.
// Launched with gridDim.y=2 (stage A, shared input table) or gridDim.y=1
// (stage B, one branch per launch -> halved live gather working set).
template<int CIN, bool BIAS>
__global__ __launch_bounds__(256, 4) void conv_mfma(
    const u16* __restrict__ X0, const u16* __restrict__ X1,
    const int* __restrict__ nbr0, const int* __restrict__ nbr1,
    const int* __restrict__ msk0, const int* __restrict__ msk1,
    const u16* __restrict__ Wt,           // [KOFF][64][CIN] bf16 (pre-offset per branch)
    const u16* __restrict__ BWt,          // [64][32] bf16 (BIAS only, pre-offset)
    u16* __restrict__ outH0, u16* __restrict__ outH1,
    float* __restrict__ st0, float* __restrict__ st1)
{
    constexpr int GSTR = CIN + 8;          // bf16 row pitch (16B-aligned)
    constexpr int NLD = CIN / 32;          // uint4 gather loads per thread (1 or 2)
    const int br = blockIdx.y;
    const u16* X = br ? X1 : X0;
    const int* nbr = br ? nbr1 : nbr0;
    const int* msk = br ? msk1 : msk0;
    const u16* Wg = Wt + (size_t)br * KOFF * 64 * CIN;
    u16* outH = br ? outH1 : outH0;
    float* st = br ? st1 : st0;

    __shared__ __align__(16) u16 sG[3][64 * GSTR];
    __shared__ __align__(16) u16 sM[BIAS ? 64 * 32 : 8];
    __shared__ float red[128];

    const int tid = threadIdx.x;
    const int n0 = blockIdx.x * 64;
    const int wv = tid >> 6;
    const int l  = tid & 63;
    const int rl = l & 15;
    const int q  = l >> 4;
    const int colbase = wv * 16;
    const int gr = tid >> 2;        // gather: 4 threads per row
    const int gc = tid & 3;

    // ---- preload all neighbor indices (mask folded to -1)
    int srcs[KOFF];
    #pragma unroll
    for (int k = 0; k < KOFF; ++k) {
        const int m  = msk[k * NVOX + n0 + gr];
        const int nb = nbr[k * NVOX + n0 + gr];
        srcs[k] = m ? nb : -1;
    }

    // ---- mask matrix for folded-BN bias MFMA (visible after loop barriers)
    if constexpr (BIAS) {
        #pragma unroll
        for (int j = 0; j < 8; ++j) {
            const int k = gc * 8 + j;
            sM[gr * 32 + k] = ((k < KOFF) && (srcs[k] >= 0)) ? (u16)0x3F80 : (u16)0;
        }
    }

    // ---- weight B-fragments (L2-hot; compiler may rematerialize under VGPR cap)
    bf16x8 wreg[KOFF][NLD];
    #pragma unroll
    for (int k = 0; k < KOFF; ++k)
        #pragma unroll
        for (int ch = 0; ch < NLD; ++ch)
            wreg[k][ch] = *(const bf16x8*)(Wg + ((size_t)k * 64 + colbase + rl) * CIN
                                           + ch * 32 + q * 8);

    uint4 g[2][NLD];
    auto issue = [&](int k, int s) {
        const int src = srcs[k];
        #pragma unroll
        for (int c = 0; c < NLD; ++c) g[s][c] = make_uint4(0u, 0u, 0u, 0u);
        if (src >= 0) {
            const u16* p = X + (size_t)src * CIN + gc * (CIN / 4);
            #pragma unroll
            for (int c = 0; c < NLD; ++c) g[s][c] = ((const uint4*)p)[c];
        }
    };
    auto store_s = [&](int k, int s) {
        u16* d = &sG[k % 3][gr * GSTR + gc * (CIN / 4)];
        #pragma unroll
        for (int c = 0; c < NLD; ++c) ((uint4*)d)[c] = g[s][c];
    };

    f32x4 acc[4] = {};
    issue(0, 0);
    issue(1, 1);
    #pragma unroll
    for (int k = 0; k < KOFF; ++k) {
        store_s(k, k & 1);                 // waits this set's loads; frees the set
        __syncthreads();                   // slot k%3 visible to all waves
        if (k + 2 < KOFF) issue(k + 2, k & 1);
        const u16* sgb = &sG[k % 3][0];
        #pragma unroll
        for (int mt = 0; mt < 4; ++mt)
            #pragma unroll
            for (int ch = 0; ch < NLD; ++ch) {
                bf16x8 afr = *(const bf16x8*)(sgb + (mt * 16 + rl) * GSTR + ch * 32 + q * 8);
                acc[mt] = __builtin_amdgcn_mfma_f32_16x16x32_bf16(afr, wreg[k][ch], acc[mt], 0, 0, 0);
            }
    }

    // ---- folded-BN bias via mask MFMA: acc += M(mask 0/1) x BW
    if constexpr (BIAS) {
        bf16x8 bw = *(const bf16x8*)(BWt + (size_t)(colbase + rl) * 32 + q * 8);
        #pragma unroll
        for (int mt = 0; mt < 4; ++mt) {
            bf16x8 mf = *(const bf16x8*)(sM + (mt * 16 + rl) * 32 + q * 8);
            acc[mt] = __builtin_amdgcn_mfma_f32_16x16x32_bf16(mf, bw, acc[mt], 0, 0, 0);
        }
    }

    // ---- epilogue: LeakyReLU -> LDS tile (reuses ring) + BN partials
    __syncthreads();                       // all MFMA LDS reads done; reuse sG
    u16* sO16 = (u16*)&sG[0][0];           // [64][72] bf16 tile (9216B)
    float ps = 0.f, pss = 0.f;
    #pragma unroll
    for (int mt = 0; mt < 4; ++mt) {
        #pragma unroll
        for (int i = 0; i < 4; ++i) {
            float v = lrelu(acc[mt][i]);
            ps += v; pss += v * v;
            const int row = mt * 16 + q * 4 + i;
            sO16[row * 72 + colbase + rl] = f2bf(v);
        }
    }
    ps  += __shfl_xor(ps, 16);  ps  += __shfl_xor(ps, 32);
    pss += __shfl_xor(pss, 16); pss += __shfl_xor(pss, 32);
    if (l < 16) { red[colbase + rl] = ps; red[64 + colbase + rl] = pss; }
    __syncthreads();

    // ---- coalesced full-line NT stores + sharded stat atomics
    #pragma unroll
    for (int p = 0; p < 2; ++p) {
        const int row = (tid >> 3) + p * 32, seg = tid & 7;
        uint4 v = *(const uint4*)(sO16 + row * 72 + seg * 8);
        __builtin_nontemporal_store(__builtin_bit_cast(u32x4v, v),
            (u32x4v*)(outH + (size_t)(n0 + row) * 64 + seg * 8));
    }
    if (tid < 128) {
        const int shard = blockIdx.x & (NSHARD - 1);
        atomicAdd(st + shard * 512 + (tid >> 6) * 64 + (tid & 63), red[tid]);
    }
}

// b<144: WtA[br][k][d][c]=bf16(W[k][c][d]);  b in [144,208): zero sharded stats;
// b>=208: feats f32 -> bf16 (into feats16), grid-stride.
__global__ void prep0(const float* __restrict__ W1, const float* __restrict__ W2,
                      const float* __restrict__ feats,
                      u16* __restrict__ WtA, float* __restrict__ stats,
                      u16* __restrict__ feats16)
{
    const int b = blockIdx.x;
    const int t = threadIdx.x;
    if (b < 144) {
        const int i = b * 256 + t;                 // 2*9*64*32 = 36864 exactly
        const int brw = i / (KOFF * 64 * 32);
        const int r  = i % (KOFF * 64 * 32);
        const int k  = r / (64 * 32);
        const int r2 = r % (64 * 32);
        const int d  = r2 / 32, c = r2 % 32;
        const float* W = brw ? W2 : W1;
        WtA[i] = f2bf(W[((size_t)k * 32 + c) * 64 + d]);
        return;
    }
    if (b < 208) {                                 // 64*256 = 16384 = NSHARD*512
        stats[(b - 144) * 256 + t] = 0.f;
        return;
    }
    const int stride = (gridDim.x - 208) * 256;
    for (int i = (b - 208) * 256 + t; i < NVOX * 32 / 8; i += stride) {
        const float4 f0 = ((const float4*)feats)[i * 2];
        const float4 f1 = ((const float4*)feats)[i * 2 + 1];
        ((uint4*)feats16)[i] = make_uint4(pkbf(f0.x, f0.y), pkbf(f0.z, f0.w),
                                          pkbf(f1.x, f1.y), pkbf(f1.z, f1.w));
    }
}

// finalize stage-A BN (sum shards, in LDS) + fold into stage-B weights:
// WtB[br][k][d][c] = bf16(W[k][c][d]*a[c]); BWt[br][d][k(pad32)] = bf16(sum_c b'[c]*W[k][c][d])
__global__ void wprepB(const float* __restrict__ W12, const float* __restrict__ W3,
                       const float* __restrict__ stats,
                       const float* __restrict__ g0, const float* __restrict__ b0,
                       const float* __restrict__ g1, const float* __restrict__ b1,
                       u16* __restrict__ WtB, u16* __restrict__ BWt)
{
    __shared__ float sa[256];                 // [br][{a[64], b'[64]}]
    const int t = threadIdx.x;
    if (t < 128) {
        const int brw = t >> 6, d = t & 63;
        float s = 0.f, ss = 0.f;
        for (int sh = 0; sh < NSHARD; ++sh) {
            s  += stats[sh * 512 + brw * 128 + d];
            ss += stats[sh * 512 + brw * 128 + 64 + d];
        }
        const float* g = brw ? g1 : g0;
        const float* bb = brw ? b1 : b0;
        const float inv_n = 1.0f / (float)NVOX;
        float mu  = s * inv_n;
        float var = ss * inv_n - mu * mu;
        float a = g[d] * rsqrtf(var + BN_EPS);
        sa[brw * 128 + d] = a;
        sa[brw * 128 + 64 + d] = bb[d] - mu * a;
    }
    __syncthreads();
    const int i = blockIdx.x * 256 + t;
    if (i >= 2 * KOFF * 64) return;
    const int brw = i / (KOFF * 64);
    const int r  = i % (KOFF * 64);
    const int k  = r / 64, d = r % 64;
    const float* W = brw ? W3 : W12;
    const float* a = sa + brw * 128;
    const float* bb = a + 64;
    float bw = 0.f;
    u16* wrow = WtB + (((size_t)brw * KOFF + k) * 64 + d) * 64;
    #pragma unroll 8
    for (int c = 0; c < 64; ++c) {
        const float wv = W[((size_t)k * 64 + c) * 64 + d];
        wrow[c] = f2bf(wv * a[c]);
        bw += wv * bb[c];
    }
    u16* brow = BWt + ((size_t)brw * 64 + d) * 32;
    brow[k] = f2bf(bw);
    if (k == 0) {
        for (int kk = KOFF; kk < 32; ++kk) brow[kk] = 0;
    }
}

// finalize stage-B BN (sum shards) + out = aff2(ys) + aff3(yrh); both inputs bf16
__global__ void combine_kernel(const u16* __restrict__ ys, const u16* __restrict__ yrh,
                               float* __restrict__ out,
                               const float* __restrict__ stats,
                               const float* __restrict__ g02, const float* __restrict__ b02,
                               const float* __restrict__ g2, const float* __restrict__ b2)
{
    __shared__ float sc[256];                 // [br][{a[64], b'[64]}]; br0=ys, br1=yrh
    const int t = threadIdx.x;
    if (t < 128) {
        const int brw = t >> 6, d = t & 63;
        float s = 0.f, ss = 0.f;
        for (int sh = 0; sh < NSHARD; ++sh) {
            s  += stats[sh * 512 + 256 + brw * 128 + d];
            ss += stats[sh * 512 + 256 + brw * 128 + 64 + d];
        }
        const float* g = brw ? g2 : g02;
        const float* b = brw ? b2 : b02;
        const float inv_n = 1.0f / (float)NVOX;
        float mu  = s * inv_n;
        float var = ss * inv_n - mu * mu;
        float a = g[d] * rsqrtf(var + BN_EPS);
        sc[brw * 128 + d] = a;
        sc[brw * 128 + 64 + d] = b[d] - mu * a;
    }
    __syncthreads();
    const int total = NVOX * 64 / 4;
    for (int i = blockIdx.x * blockDim.x + t; i < total; i += gridDim.x * blockDim.x) {
        const int dq = (i & 15) * 4;
        ushort4 sh = reinterpret_cast<const ushort4*>(ys)[i];
        ushort4 rh = reinterpret_cast<const ushort4*>(yrh)[i];
        float4 a2 = *(const float4*)(sc + dq);
        float4 b2v = *(const float4*)(sc + 64 + dq);
        float4 a3 = *(const float4*)(sc + 128 + dq);
        float4 b3v = *(const float4*)(sc + 128 + 64 + dq);
        f32x4 o;
        o.x = fmaf(a2.x, bf2f(sh.x), b2v.x) + fmaf(a3.x, bf2f(rh.x), b3v.x);
        o.y = fmaf(a2.y, bf2f(sh.y), b2v.y) + fmaf(a3.y, bf2f(rh.y), b3v.y);
        o.z = fmaf(a2.z, bf2f(sh.z), b2v.z) + fmaf(a3.z, bf2f(rh.z), b3v.z);
        o.w = fmaf(a2.w, bf2f(sh.w), b2v.w) + fmaf(a3.w, bf2f(rh.w), b3v.w);
        __builtin_nontemporal_store(o, (f32x4*)(out + (size_t)i * 4));
    }
}

extern "C" void kernel_launch(void* const* d_in, const int* in_sizes, int n_in,
                              void* d_out, int out_size, void* d_ws, size_t ws_size,
                              hipStream_t stream) {
    const float* feats = (const float*)d_in[0];
    const float* W1    = (const float*)d_in[1];
    const float* W12   = (const float*)d_in[2];
    const float* W2    = (const float*)d_in[3];
    const float* W3    = (const float*)d_in[4];
    const float* g0  = (const float*)d_in[5];
    const float* b0  = (const float*)d_in[6];
    const float* g02 = (const float*)d_in[7];
    const float* b02 = (const float*)d_in[8];
    const float* g1  = (const float*)d_in[9];
    const float* b1  = (const float*)d_in[10];
    const float* g2  = (const float*)d_in[11];
    const float* b2  = (const float*)d_in[12];
    const int* nbrA  = (const int*)d_in[13];
    const int* maskA = (const int*)d_in[14];   // bool delivered as int32
    const int* nbrB  = (const int*)d_in[15];
    const int* maskB = (const int*)d_in[16];

    // ws layout (~77 MB): region0=y1 (reused as yrh by stage-B branch r, which
    // runs AFTER branch s has fully consumed y1 — launches are stream-ordered),
    // region1=y2, region2=ys (feats16 aliases its first half; dead after stage A).
    const size_t buf = (size_t)NVOX * 64;
    u16* y1  = (u16*)d_ws;
    u16* yrh = y1;                       // branch-r bf16 output (after y1 is dead)
    u16* y2  = y1 + buf;
    u16* ys  = y2 + buf;
    u16* feats16 = ys;                   // alias (NVOX*32 u16)
    u16* WtA = ys + buf;                 // 2*9*64*32 = 36864
    u16* WtB = WtA + 2 * KOFF * 64 * 32; // 2*9*64*64 = 73728
    u16* BWt = WtB + 2 * KOFF * 64 * 64; // 2*64*32   = 4096
    float* stats = (float*)(BWt + 2 * 64 * 32);  // NSHARD x [4 x {sum[64],sumsq[64]}]

    prep0<<<2000, 256, 0, stream>>>(W1, W2, feats, WtA, stats, feats16);

    // stage A (both branches): y1 = lrelu(conv(feats,nbrA,W1)); y2 = ...(nbrB,W2)
    conv_mfma<32, false><<<dim3(NVOX / 64, 2), 256, 0, stream>>>(
        feats16, feats16, nbrA, nbrB, maskA, maskB, WtA, nullptr,
        y1, y2, stats, stats + 128);

    wprepB<<<5, 256, 0, stream>>>(W12, W3, stats, g0, b0, g1, b1, WtB, BWt);

    // stage B, branch s (sequential -> halved live gather working set):
    // ys = lrelu(conv(bn(y1),nbrB,W12))
    conv_mfma<64, true><<<dim3(NVOX / 64, 1), 256, 0, stream>>>(
        y1, nullptr, nbrB, nullptr, maskB, nullptr, WtB, BWt,
        ys, nullptr, stats + 256, nullptr);

    // stage B, branch r: yrh = lrelu(conv(bn(y2),nbrA,W3))  [y1 region is dead now]
    conv_mfma<64, true><<<dim3(NVOX / 64, 1), 256, 0, stream>>>(
        y2, nullptr, nbrA, nullptr, maskA, nullptr,
        WtB + (size_t)KOFF * 64 * 64, BWt + 64 * 32,
        yrh, nullptr, stats + 384, nullptr);

    combine_kernel<<<1024, 256, 0, stream>>>(ys, yrh, (float*)d_out, stats,
                                             g02, b02, g2, b2);
}

// Round 12
// 180.968 us; speedup vs baseline: 1.1245x; 1.0566x over previous
//
#include <hip/hip_runtime.h>

#define NVOX 200000
#define KOFF 9
#define NSHARD 32
#define BN_EPS 1e-5f

typedef unsigned short u16;
typedef __bf16 bf16x8 __attribute__((ext_vector_type(8)));
typedef float f32x4 __attribute__((ext_vector_type(4)));
typedef unsigned int u32x4v __attribute__((ext_vector_type(4)));

__device__ __forceinline__ float lrelu(float x) { return x > 0.0f ? x : 0.01f * x; }
__device__ __forceinline__ float bf2f(u16 h) { return __uint_as_float(((unsigned)h) << 16); }
__device__ __forceinline__ u16 f2bf(float x) {   // round-nearest-even
    unsigned u = __float_as_uint(x);
    u += 0x7fffu + ((u >> 16) & 1u);
    return (u16)(u >> 16);
}
__device__ __forceinline__ unsigned pkbf(float a, float b) {
    return (unsigned)f2bf(a) | ((unsigned)f2bf(b) << 16);
}

// MFMA sparse-conv (r7 ring pipeline + LDS-tile store epilogue; best structure):
//  - all 9 mask/nbr indices preloaded (independent loads)
//  - gather ring: 3 LDS slots, loads for offset k issued at iteration k-2,
//    ONE barrier per iteration
//  - BN stats: 32-way sharded atomics
//  - epilogue: acc -> LDS tile -> full-128B-line NT stores (bf16 output always)
// 64 voxels x 64 cout per block, 4 waves; wave w owns cols 16w..16w+15.
// gridDim.y=2 runs both branches in one launch (br selects per-branch data).
template<int CIN, bool BIAS>
__global__ __launch_bounds__(256, 4) void conv_mfma(
    const u16* __restrict__ X0, const u16* __restrict__ X1,
    const int* __restrict__ nbr0, const int* __restrict__ nbr1,
    const int* __restrict__ msk0, const int* __restrict__ msk1,
    const u16* __restrict__ Wt,           // [2][KOFF][64][CIN] bf16
    const u16* __restrict__ BWt,          // [2][64][32] bf16 (BIAS only)
    u16* __restrict__ outH0, u16* __restrict__ outH1,
    float* __restrict__ st0, float* __restrict__ st1)
{
    constexpr int GSTR = CIN + 8;          // bf16 row pitch (16B-aligned)
    constexpr int NLD = CIN / 32;          // uint4 gather loads per thread (1 or 2)
    const int br = blockIdx.y;
    const u16* X = br ? X1 : X0;
    const int* nbr = br ? nbr1 : nbr0;
    const int* msk = br ? msk1 : msk0;
    const u16* Wg = Wt + (size_t)br * KOFF * 64 * CIN;
    u16* outH = br ? outH1 : outH0;
    float* st = br ? st1 : st0;

    __shared__ __align__(16) u16 sG[3][64 * GSTR];
    __shared__ __align__(16) u16 sM[BIAS ? 64 * 32 : 8];
    __shared__ float red[128];

    const int tid = threadIdx.x;
    const int n0 = blockIdx.x * 64;
    const int wv = tid >> 6;
    const int l  = tid & 63;
    const int rl = l & 15;
    const int q  = l >> 4;
    const int colbase = wv * 16;
    const int gr = tid >> 2;        // gather: 4 threads per row
    const int gc = tid & 3;

    // ---- preload all neighbor indices (mask folded to -1)
    int srcs[KOFF];
    #pragma unroll
    for (int k = 0; k < KOFF; ++k) {
        const int m  = msk[k * NVOX + n0 + gr];
        const int nb = nbr[k * NVOX + n0 + gr];
        srcs[k] = m ? nb : -1;
    }

    // ---- mask matrix for folded-BN bias MFMA (visible after loop barriers)
    if constexpr (BIAS) {
        #pragma unroll
        for (int j = 0; j < 8; ++j) {
            const int k = gc * 8 + j;
            sM[gr * 32 + k] = ((k < KOFF) && (srcs[k] >= 0)) ? (u16)0x3F80 : (u16)0;
        }
    }

    // ---- weight B-fragments (L2-hot; compiler may rematerialize under VGPR cap)
    bf16x8 wreg[KOFF][NLD];
    #pragma unroll
    for (int k = 0; k < KOFF; ++k)
        #pragma unroll
        for (int ch = 0; ch < NLD; ++ch)
            wreg[k][ch] = *(const bf16x8*)(Wg + ((size_t)k * 64 + colbase + rl) * CIN
                                           + ch * 32 + q * 8);

    uint4 g[2][NLD];
    auto issue = [&](int k, int s) {
        const int src = srcs[k];
        #pragma unroll
        for (int c = 0; c < NLD; ++c) g[s][c] = make_uint4(0u, 0u, 0u, 0u);
        if (src >= 0) {
            const u16* p = X + (size_t)src * CIN + gc * (CIN / 4);
            #pragma unroll
            for (int c = 0; c < NLD; ++c) g[s][c] = ((const uint4*)p)[c];
        }
    };
    auto store_s = [&](int k, int s) {
        u16* d = &sG[k % 3][gr * GSTR + gc * (CIN / 4)];
        #pragma unroll
        for (int c = 0; c < NLD; ++c) ((uint4*)d)[c] = g[s][c];
    };

    f32x4 acc[4] = {};
    issue(0, 0);
    issue(1, 1);
    #pragma unroll
    for (int k = 0; k < KOFF; ++k) {
        store_s(k, k & 1);                 // waits this set's loads; frees the set
        __syncthreads();                   // slot k%3 visible to all waves
        if (k + 2 < KOFF) issue(k + 2, k & 1);
        const u16* sgb = &sG[k % 3][0];
        #pragma unroll
        for (int mt = 0; mt < 4; ++mt)
            #pragma unroll
            for (int ch = 0; ch < NLD; ++ch) {
                bf16x8 afr = *(const bf16x8*)(sgb + (mt * 16 + rl) * GSTR + ch * 32 + q * 8);
                acc[mt] = __builtin_amdgcn_mfma_f32_16x16x32_bf16(afr, wreg[k][ch], acc[mt], 0, 0, 0);
            }
    }

    // ---- folded-BN bias via mask MFMA: acc += M(mask 0/1) x BW
    if constexpr (BIAS) {
        bf16x8 bw = *(const bf16x8*)(BWt + ((size_t)br * 64 + colbase + rl) * 32 + q * 8);
        #pragma unroll
        for (int mt = 0; mt < 4; ++mt) {
            bf16x8 mf = *(const bf16x8*)(sM + (mt * 16 + rl) * 32 + q * 8);
            acc[mt] = __builtin_amdgcn_mfma_f32_16x16x32_bf16(mf, bw, acc[mt], 0, 0, 0);
        }
    }

    // ---- epilogue: LeakyReLU -> LDS tile (reuses ring) + BN partials
    __syncthreads();                       // all MFMA LDS reads done; reuse sG
    u16* sO16 = (u16*)&sG[0][0];           // [64][72] bf16 tile (9216B)
    float ps = 0.f, pss = 0.f;
    #pragma unroll
    for (int mt = 0; mt < 4; ++mt) {
        #pragma unroll
        for (int i = 0; i < 4; ++i) {
            float v = lrelu(acc[mt][i]);
            ps += v; pss += v * v;
            const int row = mt * 16 + q * 4 + i;
            sO16[row * 72 + colbase + rl] = f2bf(v);
        }
    }
    ps  += __shfl_xor(ps, 16);  ps  += __shfl_xor(ps, 32);
    pss += __shfl_xor(pss, 16); pss += __shfl_xor(pss, 32);
    if (l < 16) { red[colbase + rl] = ps; red[64 + colbase + rl] = pss; }
    __syncthreads();

    // ---- coalesced full-line NT stores + sharded stat atomics
    #pragma unroll
    for (int p = 0; p < 2; ++p) {
        const int row = (tid >> 3) + p * 32, seg = tid & 7;
        uint4 v = *(const uint4*)(sO16 + row * 72 + seg * 8);
        __builtin_nontemporal_store(__builtin_bit_cast(u32x4v, v),
            (u32x4v*)(outH + (size_t)(n0 + row) * 64 + seg * 8));
    }
    if (tid < 128) {
        const int shard = blockIdx.x & (NSHARD - 1);
        atomicAdd(st + shard * 512 + (tid >> 6) * 64 + (tid & 63), red[tid]);
    }
}

// b<144: WtA[br][k][d][c]=bf16(W[k][c][d]);  b in [144,208): zero sharded stats;
// b>=208: feats f32 -> bf16 (into feats16), grid-stride.
__global__ void prep0(const float* __restrict__ W1, const float* __restrict__ W2,
                      const float* __restrict__ feats,
                      u16* __restrict__ WtA, float* __restrict__ stats,
                      u16* __restrict__ feats16)
{
    const int b = blockIdx.x;
    const int t = threadIdx.x;
    if (b < 144) {
        const int i = b * 256 + t;                 // 2*9*64*32 = 36864 exactly
        const int brw = i / (KOFF * 64 * 32);
        const int r  = i % (KOFF * 64 * 32);
        const int k  = r / (64 * 32);
        const int r2 = r % (64 * 32);
        const int d  = r2 / 32, c = r2 % 32;
        const float* W = brw ? W2 : W1;
        WtA[i] = f2bf(W[((size_t)k * 32 + c) * 64 + d]);
        return;
    }
    if (b < 208) {                                 // 64*256 = 16384 = NSHARD*512
        stats[(b - 144) * 256 + t] = 0.f;
        return;
    }
    const int stride = (gridDim.x - 208) * 256;
    for (int i = (b - 208) * 256 + t; i < NVOX * 32 / 8; i += stride) {
        const float4 f0 = ((const float4*)feats)[i * 2];
        const float4 f1 = ((const float4*)feats)[i * 2 + 1];
        ((uint4*)feats16)[i] = make_uint4(pkbf(f0.x, f0.y), pkbf(f0.z, f0.w),
                                          pkbf(f1.x, f1.y), pkbf(f1.z, f1.w));
    }
}

// finalize stage-A BN (sum shards, in LDS) + fold into stage-B weights:
// WtB[br][k][d][c] = bf16(W[k][c][d]*a[c]); BWt[br][d][k(pad32)] = bf16(sum_c b'[c]*W[k][c][d])
__global__ void wprepB(const float* __restrict__ W12, const float* __restrict__ W3,
                       const float* __restrict__ stats,
                       const float* __restrict__ g0, const float* __restrict__ b0,
                       const float* __restrict__ g1, const float* __restrict__ b1,
                       u16* __restrict__ WtB, u16* __restrict__ BWt)
{
    __shared__ float sa[256];                 // [br][{a[64], b'[64]}]
    const int t = threadIdx.x;
    if (t < 128) {
        const int brw = t >> 6, d = t & 63;
        float s = 0.f, ss = 0.f;
        for (int sh = 0; sh < NSHARD; ++sh) {
            s  += stats[sh * 512 + brw * 128 + d];
            ss += stats[sh * 512 + brw * 128 + 64 + d];
        }
        const float* g = brw ? g1 : g0;
        const float* bb = brw ? b1 : b0;
        const float inv_n = 1.0f / (float)NVOX;
        float mu  = s * inv_n;
        float var = ss * inv_n - mu * mu;
        float a = g[d] * rsqrtf(var + BN_EPS);
        sa[brw * 128 + d] = a;
        sa[brw * 128 + 64 + d] = bb[d] - mu * a;
    }
    __syncthreads();
    const int i = blockIdx.x * 256 + t;
    if (i >= 2 * KOFF * 64) return;
    const int brw = i / (KOFF * 64);
    const int r  = i % (KOFF * 64);
    const int k  = r / 64, d = r % 64;
    const float* W = brw ? W3 : W12;
    const float* a = sa + brw * 128;
    const float* bb = a + 64;
    float bw = 0.f;
    u16* wrow = WtB + (((size_t)brw * KOFF + k) * 64 + d) * 64;
    #pragma unroll 8
    for (int c = 0; c < 64; ++c) {
        const float wv = W[((size_t)k * 64 + c) * 64 + d];
        wrow[c] = f2bf(wv * a[c]);
        bw += wv * bb[c];
    }
    u16* brow = BWt + ((size_t)brw * 64 + d) * 32;
    brow[k] = f2bf(bw);
    if (k == 0) {
        for (int kk = KOFF; kk < 32; ++kk) brow[kk] = 0;
    }
}

// finalize stage-B BN (sum shards) + out = aff2(ys) + aff3(yrh); both inputs bf16
__global__ void combine_kernel(const u16* __restrict__ ys, const u16* __restrict__ yrh,
                               float* __restrict__ out,
                               const float* __restrict__ stats,
                               const float* __restrict__ g02, const float* __restrict__ b02,
                               const float* __restrict__ g2, const float* __restrict__ b2)
{
    __shared__ float sc[256];                 // [br][{a[64], b'[64]}]; br0=ys, br1=yrh
    const int t = threadIdx.x;
    if (t < 128) {
        const int brw = t >> 6, d = t & 63;
        float s = 0.f, ss = 0.f;
        for (int sh = 0; sh < NSHARD; ++sh) {
            s  += stats[sh * 512 + 256 + brw * 128 + d];
            ss += stats[sh * 512 + 256 + brw * 128 + 64 + d];
        }
        const float* g = brw ? g2 : g02;
        const float* b = brw ? b2 : b02;
        const float inv_n = 1.0f / (float)NVOX;
        float mu  = s * inv_n;
        float var = ss * inv_n - mu * mu;
        float a = g[d] * rsqrtf(var + BN_EPS);
        sc[brw * 128 + d] = a;
        sc[brw * 128 + 64 + d] = b[d] - mu * a;
    }
    __syncthreads();
    const int total = NVOX * 64 / 4;
    for (int i = blockIdx.x * blockDim.x + t; i < total; i += gridDim.x * blockDim.x) {
        const int dq = (i & 15) * 4;
        ushort4 sh = reinterpret_cast<const ushort4*>(ys)[i];
        ushort4 rh = reinterpret_cast<const ushort4*>(yrh)[i];
        float4 a2 = *(const float4*)(sc + dq);
        float4 b2v = *(const float4*)(sc + 64 + dq);
        float4 a3 = *(const float4*)(sc + 128 + dq);
        float4 b3v = *(const float4*)(sc + 128 + 64 + dq);
        f32x4 o;
        o.x = fmaf(a2.x, bf2f(sh.x), b2v.x) + fmaf(a3.x, bf2f(rh.x), b3v.x);
        o.y = fmaf(a2.y, bf2f(sh.y), b2v.y) + fmaf(a3.y, bf2f(rh.y), b3v.y);
        o.z = fmaf(a2.z, bf2f(sh.z), b2v.z) + fmaf(a3.z, bf2f(rh.z), b3v.z);
        o.w = fmaf(a2.w, bf2f(sh.w), b2v.w) + fmaf(a3.w, bf2f(rh.w), b3v.w);
        __builtin_nontemporal_store(o, (f32x4*)(out + (size_t)i * 4));
    }
}

extern "C" void kernel_launch(void* const* d_in, const int* in_sizes, int n_in,
                              void* d_out, int out_size, void* d_ws, size_t ws_size,
                              hipStream_t stream) {
    const float* feats = (const float*)d_in[0];
    const float* W1    = (const float*)d_in[1];
    const float* W12   = (const float*)d_in[2];
    const float* W2    = (const float*)d_in[3];
    const float* W3    = (const float*)d_in[4];
    const float* g0  = (const float*)d_in[5];
    const float* b0  = (const float*)d_in[6];
    const float* g02 = (const float*)d_in[7];
    const float* b02 = (const float*)d_in[8];
    const float* g1  = (const float*)d_in[9];
    const float* b1  = (const float*)d_in[10];
    const float* g2  = (const float*)d_in[11];
    const float* b2  = (const float*)d_in[12];
    const int* nbrA  = (const int*)d_in[13];
    const int* maskA = (const int*)d_in[14];   // bool delivered as int32
    const int* nbrB  = (const int*)d_in[15];
    const int* maskB = (const int*)d_in[16];

    // ws layout: y1, y2, ys, [yrh], weights, sharded stats.
    // Preferred (combined stage-B): 4 bf16 tables = ~103 MB. If ws is too
    // small, fall back to sequential stage-B with yrh aliasing y1 (~77 MB).
    const size_t buf = (size_t)NVOX * 64;
    const size_t wtab = 2 * KOFF * 64 * 32 + 2 * KOFF * 64 * 64 + 2 * 64 * 32;
    const size_t need4 = (4 * buf + wtab) * sizeof(u16) + (size_t)NSHARD * 512 * 4 + 1024;
    const bool combined = ws_size >= need4;

    u16* y1  = (u16*)d_ws;
    u16* y2  = y1 + buf;
    u16* ys  = y2 + buf;
    u16* feats16 = ys;                   // alias (NVOX*32 u16); dead after stage A
    u16* yrh = combined ? (ys + buf) : y1;   // branch-r output
    u16* WtA = combined ? (yrh + buf) : (ys + buf);
    u16* WtB = WtA + 2 * KOFF * 64 * 32;
    u16* BWt = WtB + 2 * KOFF * 64 * 64;
    float* stats = (float*)(BWt + 2 * 64 * 32);  // NSHARD x [4 x {sum[64],sumsq[64]}]

    prep0<<<2000, 256, 0, stream>>>(W1, W2, feats, WtA, stats, feats16);

    // stage A (both branches): y1 = lrelu(conv(feats,nbrA,W1)); y2 = ...(nbrB,W2)
    conv_mfma<32, false><<<dim3(NVOX / 64, 2), 256, 0, stream>>>(
        feats16, feats16, nbrA, nbrB, maskA, maskB, WtA, nullptr,
        y1, y2, stats, stats + 128);

    wprepB<<<5, 256, 0, stream>>>(W12, W3, stats, g0, b0, g1, b1, WtB, BWt);

    if (combined) {
        // stage B combined: ys = lrelu(conv(bn(y1),nbrB,W12));
        //                   yrh = lrelu(conv(bn(y2),nbrA,W3))
        conv_mfma<64, true><<<dim3(NVOX / 64, 2), 256, 0, stream>>>(
            y1, y2, nbrB, nbrA, maskB, maskA, WtB, BWt,
            ys, yrh, stats + 256, stats + 384);
    } else {
        // sequential fallback (yrh aliases y1; branch r runs after y1 is dead)
        conv_mfma<64, true><<<dim3(NVOX / 64, 1), 256, 0, stream>>>(
            y1, nullptr, nbrB, nullptr, maskB, nullptr, WtB, BWt,
            ys, nullptr, stats + 256, nullptr);
        conv_mfma<64, true><<<dim3(NVOX / 64, 1), 256, 0, stream>>>(
            y2, nullptr, nbrA, nullptr, maskA, nullptr,
            WtB + (size_t)KOFF * 64 * 64, BWt + 64 * 32,
            yrh, nullptr, stats + 384, nullptr);
    }

    combine_kernel<<<1024, 256, 0, stream>>>(ys, yrh, (float*)d_out, stats,
                                             g02, b02, g2, b2);
}